// Round 6
// baseline (128.361 us; speedup 1.0000x reference)
//
#include <hip/hip_runtime.h>
#include <hip/hip_fp16.h>

// PointSpatialTransformer: bilinear gather of normalized-flow field at 4M points.
// H = W = 512.
// Round-6 design (force memory-level parallelism):
//  * 4 MB quad table T[512][512] (uint4): all 4 bilinear corners as 4 x half2
//    -> ONE 16B gather per point.
//  * 8 points/thread; all 8 gathers issued, then sched_barrier(0) so the
//    compiler cannot interleave consume into the load group (round-5 failure:
//    VGPR_Count=20 proved loads were serialized to ~2 outstanding/wave;
//    kernel is latency*concurrency bound, not request bound).
//  * __launch_bounds__(256,2): allow up to ~128 VGPRs, keep >=16 waves/CU.

constexpr int HH = 512;
constexpr int WW = 512;

typedef float f32x4 __attribute__((ext_vector_type(4)));

__device__ __forceinline__ float Lx_val(const float* __restrict__ flow, int i, int j) {
    const float s = 2.0f / 511.0f;
    return fmaf((float)j + flow[(i << 9) + j + HH * WW], s, -1.0f);  // ch1
}
__device__ __forceinline__ float Ly_val(const float* __restrict__ flow, int i, int j) {
    const float s = 2.0f / 511.0f;
    return fmaf((float)i + flow[(i << 9) + j], s, -1.0f);            // ch0
}

__device__ __forceinline__ unsigned int pack_corner(const float* __restrict__ flow,
                                                    int i, int j) {
    __half2 h = __float22half2_rn(make_float2(Lx_val(flow, i, j), Ly_val(flow, i, j)));
    return *reinterpret_cast<unsigned int*>(&h);
}

// ---------------- Kernel 1: build quad table (4 MB) ----------------
__global__ __launch_bounds__(256) void build_T_kernel(const float* __restrict__ flow,
                                                      uint4* __restrict__ T) {
    int idx = blockIdx.x * 256 + threadIdx.x;   // 0 .. 262143
    int i = idx >> 9;
    int j = idx & 511;
    int ip = min(i + 1, 511);
    int jp = min(j + 1, 511);
    uint4 e;
    e.x = pack_corner(flow, i,  j);    // v00
    e.y = pack_corner(flow, i,  jp);   // v01
    e.z = pack_corner(flow, ip, j);    // v10
    e.w = pack_corner(flow, ip, jp);   // v11
    T[idx] = e;
}

__device__ __forceinline__ float2 h2f(unsigned int u) {
    __half2 h = *reinterpret_cast<__half2*>(&u);
    return __half22float2(h);
}

// bilinear combine + output affine; reference weight/corner pairing verbatim
__device__ __forceinline__ float2 combine4(uint4 e, float xf, float yf) {
    float2 v00 = h2f(e.x);
    float2 v01 = h2f(e.y);
    float2 v10 = h2f(e.z);
    float2 v11 = h2f(e.w);
    float w00 = xf * yf;
    float w10 = xf * (1.0f - yf);
    float w01 = (1.0f - xf) * yf;
    float w11 = (1.0f - xf) * (1.0f - yf);
    float tx = w00 * v00.x + w10 * v10.x + w01 * v01.x + w11 * v11.x;
    float ty = w00 * v00.y + w10 * v10.y + w01 * v01.y + w11 * v11.y;
    return make_float2((ty + 1.0f) * 256.0f, (tx + 1.0f) * 256.0f);
}

__device__ __forceinline__ float2 point_scalar(const uint4* __restrict__ T,
                                               float x, float y, bool bil) {
    if (bil) {
        float xt = truncf(x), yt = truncf(y);
        int x0 = (int)xt, y0 = (int)yt;
        return combine4(T[(x0 << 9) + y0], x - xt, y - yt);
    } else {
        int xi = min((int)rintf(x), 511);
        int yi = min((int)rintf(y), 511);
        float2 t = h2f(T[(xi << 9) + yi].x);
        return make_float2((t.y + 1.0f) * 256.0f, (t.x + 1.0f) * 256.0f);
    }
}

// ---------------- Kernel 2: 8 points/thread, batched gathers ----------------
__global__ __launch_bounds__(256, 2) void pst_kernel(const float* __restrict__ point,
                                                     const uint4* __restrict__ T,
                                                     const int* __restrict__ intep,
                                                     float* __restrict__ out,
                                                     int n /* number of points */) {
    const bool bil = (*intep != 0);
    int tid = blockIdx.x * 256 + threadIdx.x;
    int base = tid * 8;                        // first point this thread owns

    if (base + 7 < n) {
        const f32x4* pts  = reinterpret_cast<const f32x4*>(point);
        f32x4*       out4 = reinterpret_cast<f32x4*>(out);
        // four independent 16B point loads (8 points)
        f32x4 p0 = pts[tid * 4 + 0];
        f32x4 p1 = pts[tid * 4 + 1];
        f32x4 p2 = pts[tid * 4 + 2];
        f32x4 p3 = pts[tid * 4 + 3];
        float x[8] = {p0.x, p0.z, p1.x, p1.z, p2.x, p2.z, p3.x, p3.z};
        float y[8] = {p0.y, p0.w, p1.y, p1.w, p2.y, p2.w, p3.y, p3.w};

        if (bil) {
            float xf[8], yf[8];
            int idx[8];
#pragma unroll
            for (int k = 0; k < 8; ++k) {
                float xt = truncf(x[k]), yt = truncf(y[k]);
                xf[k] = x[k] - xt;
                yf[k] = y[k] - yt;
                idx[k] = ((int)xt << 9) + (int)yt;
            }
            // issue all 8 gathers; barrier forbids interleaving consume into them
            uint4 e[8];
#pragma unroll
            for (int k = 0; k < 8; ++k) e[k] = T[idx[k]];
            __builtin_amdgcn_sched_barrier(0);

            float2 r[8];
#pragma unroll
            for (int k = 0; k < 8; ++k) r[k] = combine4(e[k], xf[k], yf[k]);

#pragma unroll
            for (int q = 0; q < 4; ++q) {
                f32x4 o = {r[2 * q].x, r[2 * q].y, r[2 * q + 1].x, r[2 * q + 1].y};
                __builtin_nontemporal_store(o, &out4[tid * 4 + q]);
            }
        } else {
            const unsigned int* Tw = reinterpret_cast<const unsigned int*>(T);
            unsigned int v[8];
#pragma unroll
            for (int k = 0; k < 8; ++k) {
                int xi = min((int)rintf(x[k]), 511);
                int yi = min((int)rintf(y[k]), 511);
                v[k] = Tw[(((xi << 9) + yi) << 2)];   // .x word of uint4
            }
            __builtin_amdgcn_sched_barrier(0);
#pragma unroll
            for (int q = 0; q < 4; ++q) {
                float2 ta = h2f(v[2 * q]);
                float2 tb = h2f(v[2 * q + 1]);
                f32x4 o = {(ta.y + 1.0f) * 256.0f, (ta.x + 1.0f) * 256.0f,
                           (tb.y + 1.0f) * 256.0f, (tb.x + 1.0f) * 256.0f};
                __builtin_nontemporal_store(o, &out4[tid * 4 + q]);
            }
        }
    } else if (base < n) {
        // tail: per-point scalar path
        const float2* pt2  = reinterpret_cast<const float2*>(point);
        float2*       out2 = reinterpret_cast<float2*>(out);
        for (int k = base; k < n; ++k) {
            float2 p = pt2[k];
            out2[k] = point_scalar(T, p.x, p.y, bil);
        }
    }
}

extern "C" void kernel_launch(void* const* d_in, const int* in_sizes, int n_in,
                              void* d_out, int out_size, void* d_ws, size_t ws_size,
                              hipStream_t stream) {
    const float* point = (const float*)d_in[0];  // (1, N, 2)
    const float* flow  = (const float*)d_in[1];  // (1, 2, 512, 512)
    const int*   intep = (const int*)d_in[2];    // scalar
    float* out = (float*)d_out;                  // (1, N, 2)

    const int n = in_sizes[0] / 2;               // number of points

    uint4* T = (uint4*)d_ws;                     // 4 MB table in workspace

    build_T_kernel<<<HH * WW / 256, 256, 0, stream>>>(flow, T);

    int nthreads = (n + 7) / 8;
    int blocks = (nthreads + 255) / 256;
    if (blocks < 1) blocks = 1;
    pst_kernel<<<blocks, 256, 0, stream>>>(point, T, intep, out, n);
}

// Round 7
// 112.800 us; speedup vs baseline: 1.1380x; 1.1380x over previous
//
#include <hip/hip_runtime.h>
#include <hip/hip_fp16.h>

// PointSpatialTransformer: bilinear gather of normalized-flow field at 4M points.
// H = W = 512.
// Round-7 design (MLP + coalescing):
//  * 4 MB quad table T[512][512] (uint4): all 4 bilinear corners as 4 x half2
//    -> ONE 16B gather per point.
//  * 8 points/thread in INTERLEAVED (wave-strided) layout: thread handles f32x4
//    slots {blockBase + k*256 + tid}, so each load/store instruction is 64
//    contiguous 16B lanes (full 64B lines; round-6's blocked layout caused
//    2.5x HBM amplification: partial-line nt stores did RMW at HBM).
//  * all 4 point loads + 8 gathers issued before any consume (sched_barrier).

constexpr int HH = 512;
constexpr int WW = 512;

typedef float f32x4 __attribute__((ext_vector_type(4)));

__device__ __forceinline__ float Lx_val(const float* __restrict__ flow, int i, int j) {
    const float s = 2.0f / 511.0f;
    return fmaf((float)j + flow[(i << 9) + j + HH * WW], s, -1.0f);  // ch1
}
__device__ __forceinline__ float Ly_val(const float* __restrict__ flow, int i, int j) {
    const float s = 2.0f / 511.0f;
    return fmaf((float)i + flow[(i << 9) + j], s, -1.0f);            // ch0
}

__device__ __forceinline__ unsigned int pack_corner(const float* __restrict__ flow,
                                                    int i, int j) {
    __half2 h = __float22half2_rn(make_float2(Lx_val(flow, i, j), Ly_val(flow, i, j)));
    return *reinterpret_cast<unsigned int*>(&h);
}

// ---------------- Kernel 1: build quad table (4 MB) ----------------
__global__ __launch_bounds__(256) void build_T_kernel(const float* __restrict__ flow,
                                                      uint4* __restrict__ T) {
    int idx = blockIdx.x * 256 + threadIdx.x;   // 0 .. 262143
    int i = idx >> 9;
    int j = idx & 511;
    int ip = min(i + 1, 511);
    int jp = min(j + 1, 511);
    uint4 e;
    e.x = pack_corner(flow, i,  j);    // v00
    e.y = pack_corner(flow, i,  jp);   // v01
    e.z = pack_corner(flow, ip, j);    // v10
    e.w = pack_corner(flow, ip, jp);   // v11
    T[idx] = e;
}

__device__ __forceinline__ float2 h2f(unsigned int u) {
    __half2 h = *reinterpret_cast<__half2*>(&u);
    return __half22float2(h);
}

// bilinear combine + output affine; reference weight/corner pairing verbatim
__device__ __forceinline__ float2 combine4(uint4 e, float xf, float yf) {
    float2 v00 = h2f(e.x);
    float2 v01 = h2f(e.y);
    float2 v10 = h2f(e.z);
    float2 v11 = h2f(e.w);
    float w00 = xf * yf;
    float w10 = xf * (1.0f - yf);
    float w01 = (1.0f - xf) * yf;
    float w11 = (1.0f - xf) * (1.0f - yf);
    float tx = w00 * v00.x + w10 * v10.x + w01 * v01.x + w11 * v11.x;
    float ty = w00 * v00.y + w10 * v10.y + w01 * v01.y + w11 * v11.y;
    return make_float2((ty + 1.0f) * 256.0f, (tx + 1.0f) * 256.0f);
}

__device__ __forceinline__ float2 point_scalar(const uint4* __restrict__ T,
                                               float x, float y, bool bil) {
    if (bil) {
        float xt = truncf(x), yt = truncf(y);
        int x0 = (int)xt, y0 = (int)yt;
        return combine4(T[(x0 << 9) + y0], x - xt, y - yt);
    } else {
        int xi = min((int)rintf(x), 511);
        int yi = min((int)rintf(y), 511);
        float2 t = h2f(T[(xi << 9) + yi].x);
        return make_float2((t.y + 1.0f) * 256.0f, (t.x + 1.0f) * 256.0f);
    }
}

// process one f32x4 slot (2 points) -> one f32x4 output
__device__ __forceinline__ f32x4 slot2(const uint4* __restrict__ T, f32x4 p, bool bil) {
    float2 r0 = point_scalar(T, p.x, p.y, bil);
    float2 r1 = point_scalar(T, p.z, p.w, bil);
    return f32x4{r0.x, r0.y, r1.x, r1.y};
}

// ---------------- Kernel 2: 8 points/thread, interleaved coalesced ----------------
__global__ __launch_bounds__(256) void pst_kernel(const float* __restrict__ point,
                                                  const uint4* __restrict__ T,
                                                  const int* __restrict__ intep,
                                                  float* __restrict__ out,
                                                  int n /* number of points */) {
    const bool bil = (*intep != 0);
    const int nquads = n >> 1;                     // f32x4 slots (2 points each)
    const int slot0 = blockIdx.x * 1024 + threadIdx.x;   // + k*256, k=0..3

    const f32x4* pts  = reinterpret_cast<const f32x4*>(point);
    f32x4*       out4 = reinterpret_cast<f32x4*>(out);

    if (slot0 + 768 < nquads) {
        // fast path: all 4 slots valid; every instruction fully coalesced
        f32x4 p0 = __builtin_nontemporal_load(&pts[slot0]);
        f32x4 p1 = __builtin_nontemporal_load(&pts[slot0 + 256]);
        f32x4 p2 = __builtin_nontemporal_load(&pts[slot0 + 512]);
        f32x4 p3 = __builtin_nontemporal_load(&pts[slot0 + 768]);

        float x[8] = {p0.x, p0.z, p1.x, p1.z, p2.x, p2.z, p3.x, p3.z};
        float y[8] = {p0.y, p0.w, p1.y, p1.w, p2.y, p2.w, p3.y, p3.w};

        if (bil) {
            float xf[8], yf[8];
            int idx[8];
#pragma unroll
            for (int k = 0; k < 8; ++k) {
                float xt = truncf(x[k]), yt = truncf(y[k]);
                xf[k] = x[k] - xt;
                yf[k] = y[k] - yt;
                idx[k] = ((int)xt << 9) + (int)yt;
            }
            // all 8 gathers in flight before any consume
            uint4 e[8];
#pragma unroll
            for (int k = 0; k < 8; ++k) e[k] = T[idx[k]];
            __builtin_amdgcn_sched_barrier(0);

            float2 r[8];
#pragma unroll
            for (int k = 0; k < 8; ++k) r[k] = combine4(e[k], xf[k], yf[k]);

            __builtin_nontemporal_store(f32x4{r[0].x, r[0].y, r[1].x, r[1].y}, &out4[slot0]);
            __builtin_nontemporal_store(f32x4{r[2].x, r[2].y, r[3].x, r[3].y}, &out4[slot0 + 256]);
            __builtin_nontemporal_store(f32x4{r[4].x, r[4].y, r[5].x, r[5].y}, &out4[slot0 + 512]);
            __builtin_nontemporal_store(f32x4{r[6].x, r[6].y, r[7].x, r[7].y}, &out4[slot0 + 768]);
        } else {
            const unsigned int* Tw = reinterpret_cast<const unsigned int*>(T);
            unsigned int v[8];
#pragma unroll
            for (int k = 0; k < 8; ++k) {
                int xi = min((int)rintf(x[k]), 511);
                int yi = min((int)rintf(y[k]), 511);
                v[k] = Tw[(((xi << 9) + yi) << 2)];   // .x word of uint4
            }
            __builtin_amdgcn_sched_barrier(0);
            float2 t[8];
#pragma unroll
            for (int k = 0; k < 8; ++k) t[k] = h2f(v[k]);
            __builtin_nontemporal_store(
                f32x4{(t[0].y + 1.0f) * 256.0f, (t[0].x + 1.0f) * 256.0f,
                      (t[1].y + 1.0f) * 256.0f, (t[1].x + 1.0f) * 256.0f}, &out4[slot0]);
            __builtin_nontemporal_store(
                f32x4{(t[2].y + 1.0f) * 256.0f, (t[2].x + 1.0f) * 256.0f,
                      (t[3].y + 1.0f) * 256.0f, (t[3].x + 1.0f) * 256.0f}, &out4[slot0 + 256]);
            __builtin_nontemporal_store(
                f32x4{(t[4].y + 1.0f) * 256.0f, (t[4].x + 1.0f) * 256.0f,
                      (t[5].y + 1.0f) * 256.0f, (t[5].x + 1.0f) * 256.0f}, &out4[slot0 + 512]);
            __builtin_nontemporal_store(
                f32x4{(t[6].y + 1.0f) * 256.0f, (t[6].x + 1.0f) * 256.0f,
                      (t[7].y + 1.0f) * 256.0f, (t[7].x + 1.0f) * 256.0f}, &out4[slot0 + 768]);
        }
    } else {
        // boundary block: per-slot guard
#pragma unroll
        for (int k = 0; k < 4; ++k) {
            int s = slot0 + k * 256;
            if (s < nquads) {
                f32x4 p = pts[s];
                out4[s] = slot2(T, p, bil);
            }
        }
        // odd final point
        if ((n & 1) && slot0 == 0 && blockIdx.x == gridDim.x - 1) {
            const float2* pt2  = reinterpret_cast<const float2*>(point);
            float2*       out2 = reinterpret_cast<float2*>(out);
            float2 p = pt2[n - 1];
            out2[n - 1] = point_scalar(T, p.x, p.y, bil);
        }
    }
}

extern "C" void kernel_launch(void* const* d_in, const int* in_sizes, int n_in,
                              void* d_out, int out_size, void* d_ws, size_t ws_size,
                              hipStream_t stream) {
    const float* point = (const float*)d_in[0];  // (1, N, 2)
    const float* flow  = (const float*)d_in[1];  // (1, 2, 512, 512)
    const int*   intep = (const int*)d_in[2];    // scalar
    float* out = (float*)d_out;                  // (1, N, 2)

    const int n = in_sizes[0] / 2;               // number of points

    uint4* T = (uint4*)d_ws;                     // 4 MB table in workspace

    build_T_kernel<<<HH * WW / 256, 256, 0, stream>>>(flow, T);

    const int nquads = n >> 1;
    int blocks = (nquads + 1023) / 1024;
    if (blocks < 1) blocks = 1;
    pst_kernel<<<blocks, 256, 0, stream>>>(point, T, intep, out, n);
}